// Round 4
// baseline (91.507 us; speedup 1.0000x reference)
//
#include <hip/hip_runtime.h>
#include <hip/hip_bf16.h>

#define BB   8192
#define SS   64
#define NIN  128
#define NH   64
#define NB   8            // batches per block (fused kernel)
#define GRID (BB / NB)    // 1024 = 4 blocks/CU exactly

typedef __attribute__((ext_vector_type(8))) short  short8;
typedef __attribute__((ext_vector_type(4))) float  f32x4;

__device__ __forceinline__ unsigned short f2b(float f) {
    unsigned int u = __float_as_uint(f);
    u += 0x7FFF + ((u >> 16) & 1);          // RNE
    return (unsigned short)(u >> 16);
}

__device__ __forceinline__ short8 cvt8(float4 x0, float4 x1) {
    short8 r;
    r[0] = (short)f2b(x0.x); r[1] = (short)f2b(x0.y);
    r[2] = (short)f2b(x0.z); r[3] = (short)f2b(x0.w);
    r[4] = (short)f2b(x1.x); r[5] = (short)f2b(x1.y);
    r[6] = (short)f2b(x1.z); r[7] = (short)f2b(x1.w);
    return r;
}

// ---- kernel 0: W_bil -> bf16 fragment order (B-operand: k=i, n=j)
// wsB[((kk*4+nt)*64 + g*16+m)*8 + e] = W_bil[32kk+8g+e][16nt+m]
__global__ void conv_wbil(const float* __restrict__ wbil, unsigned short* __restrict__ wsB) {
    int q = blockIdx.x * blockDim.x + threadIdx.x;
    if (q < NH * NH) {
        int i = q >> 6, j = q & 63;
        int kk = i >> 5, g = (i >> 3) & 3, e = i & 7, nt = j >> 4, m = j & 15;
        wsB[(((kk * 4 + nt) * 64) + g * 16 + m) * 8 + e] = f2b(wbil[q]);
    }
}

// ---- kernel 1: persistent fused GCN, ONE barrier per iteration ----
__global__ __launch_bounds__(256, 4) void fused_gcn(
    const float* __restrict__ seq1, const float* __restrict__ adj,
    const float* __restrict__ W_fc, const float* __restrict__ b_gcn,
    const float* __restrict__ prelu_a, float* __restrict__ out_hmv,
    float* __restrict__ out_c)
{
    __shared__ short8 Wlds[1024];                 // 16 KiB fragment-ordered W_fc
    __shared__ unsigned short ftsT[2][NH][72];    // 18 KiB double-buffered [h][s]
    __shared__ float c_part[2][4][NH];            //  2 KiB double-buffered

    const int tid = threadIdx.x;
    const int w   = tid >> 6;
    const int l   = tid & 63;
    const int m   = l & 15;
    const int g   = l >> 4;
    const int bbase = blockIdx.x * NB;
    const int srow  = 16 * w + m;
    const int s0i   = 16 * w + 4 * g;

    // ---- prologue: issue batch-0 prefetch FIRST (deepest in queue) ----
    float4 s0, s1, s2, s3, s4, s5, s6, s7;
    float4 a0, a1, a2, a3;
    {
        const float4* sp = reinterpret_cast<const float4*>(seq1 + (size_t)bbase * (SS * NIN) + srow * NIN);
        s0 = sp[0 + 2 * g];  s1 = sp[1 + 2 * g];
        s2 = sp[8 + 2 * g];  s3 = sp[9 + 2 * g];
        s4 = sp[16 + 2 * g]; s5 = sp[17 + 2 * g];
        s6 = sp[24 + 2 * g]; s7 = sp[25 + 2 * g];
        const float4* ap = reinterpret_cast<const float4*>(adj + (size_t)bbase * (SS * SS) + srow * SS);
        a0 = ap[0 + 2 * g]; a1 = ap[1 + 2 * g];
        a2 = ap[8 + 2 * g]; a3 = ap[9 + 2 * g];
    }

    // ---- build W fragments in-block (W_fc is L2-resident): wave w owns hj=w ----
    #pragma unroll
    for (int kk = 0; kk < 4; ++kk) {
        const float4* wp = reinterpret_cast<const float4*>(W_fc + (16 * w + m) * NIN + 32 * kk + 8 * g);
        Wlds[(w * 4 + kk) * 64 + l] = cvt8(wp[0], wp[1]);
    }

    const float pa = *prelu_a;
    float bg[4];
    #pragma unroll
    for (int hj = 0; hj < 4; ++hj) bg[hj] = b_gcn[16 * hj + m];

    // raw barrier: W staged; batch-0 prefetch stays in flight
    asm volatile("s_waitcnt lgkmcnt(0)" ::: "memory");
    __builtin_amdgcn_s_barrier();
    asm volatile("" ::: "memory");

    #pragma unroll 1
    for (int j = 0; j < NB; ++j) {
        const int b = bbase + j;
        const int p = j & 1;

        // 1. cvt seq(j)  [counted vmcnt: adj(j) stays outstanding]
        short8 af[4];
        af[0] = cvt8(s0, s1); af[1] = cvt8(s2, s3);
        af[2] = cvt8(s4, s5); af[3] = cvt8(s6, s7);

        // 2. issue seq(j+1)
        if (j + 1 < NB) {
            const float4* sp = reinterpret_cast<const float4*>(seq1 + (size_t)(b + 1) * (SS * NIN) + srow * NIN);
            s0 = sp[0 + 2 * g];  s1 = sp[1 + 2 * g];
            s2 = sp[8 + 2 * g];  s3 = sp[9 + 2 * g];
            s4 = sp[16 + 2 * g]; s5 = sp[17 + 2 * g];
            s6 = sp[24 + 2 * g]; s7 = sp[25 + 2 * g];
        }

        // 3. GEMM1: fts[s][h] = sum_i seq[s][i] * W_fc[h][i]
        f32x4 acc1[4];
        #pragma unroll
        for (int hj = 0; hj < 4; ++hj)
            for (int r = 0; r < 4; ++r) acc1[hj][r] = 0.f;
        #pragma unroll
        for (int hj = 0; hj < 4; ++hj) {
            #pragma unroll
            for (int kk = 0; kk < 4; ++kk) {
                short8 bf = Wlds[(hj * 4 + kk) * 64 + l];
                acc1[hj] = __builtin_amdgcn_mfma_f32_16x16x32_bf16(af[kk], bf, acc1[hj], 0, 0, 0);
            }
        }

        // 4. cvt adj(j)  [counted vmcnt: seq(j+1) stays outstanding]
        short8 adf0 = cvt8(a0, a1);
        short8 adf1 = cvt8(a2, a3);

        // 5. issue adj(j+1)  (regs just died -> same VGPRs, full-iteration latency cover)
        if (j + 1 < NB) {
            const float4* ap = reinterpret_cast<const float4*>(adj + (size_t)(b + 1) * (SS * SS) + srow * SS);
            a0 = ap[0 + 2 * g]; a1 = ap[1 + 2 * g];
            a2 = ap[8 + 2 * g]; a3 = ap[9 + 2 * g];
        }

        // 6. pack + transpose-write fts^T to LDS buffer p
        #pragma unroll
        for (int hj = 0; hj < 4; ++hj) {
            uint2 pk;
            pk.x = (unsigned)f2b(acc1[hj][0]) | ((unsigned)f2b(acc1[hj][1]) << 16);
            pk.y = (unsigned)f2b(acc1[hj][2]) | ((unsigned)f2b(acc1[hj][3]) << 16);
            *reinterpret_cast<uint2*>(&ftsT[p][16 * hj + m][s0i]) = pk;
        }

        // 7. the ONLY barrier this iteration (no vmcnt drain)
        asm volatile("s_waitcnt lgkmcnt(0)" ::: "memory");
        __builtin_amdgcn_s_barrier();
        asm volatile("" ::: "memory");

        // 8. GEMM2: out[s][h] = sum_t adj[s][t] * fts[t][h]
        f32x4 acc2[4];
        #pragma unroll
        for (int hj = 0; hj < 4; ++hj)
            for (int r = 0; r < 4; ++r) acc2[hj][r] = 0.f;
        #pragma unroll
        for (int hj = 0; hj < 4; ++hj) {
            short8 f0 = *reinterpret_cast<const short8*>(&ftsT[p][16 * hj + m][8 * g]);
            short8 f1 = *reinterpret_cast<const short8*>(&ftsT[p][16 * hj + m][8 * g + 32]);
            acc2[hj] = __builtin_amdgcn_mfma_f32_16x16x32_bf16(adf0, f0, acc2[hj], 0, 0, 0);
            acc2[hj] = __builtin_amdgcn_mfma_f32_16x16x32_bf16(adf1, f1, acc2[hj], 0, 0, 0);
        }

        // 9. bias + PReLU + strip sums + h_mv row
        #pragma unroll
        for (int hj = 0; hj < 4; ++hj) {
            const int h = 16 * hj + m;
            float part = 0.f;
            #pragma unroll
            for (int r = 0; r < 4; ++r) {
                float v = acc2[hj][r] + bg[hj];
                v = (v >= 0.f) ? v : pa * v;
                const int s = s0i + r;
                if (s < SS - 1) part += v;
                else            out_hmv[(size_t)b * NH + h] = v;  // s == 63
            }
            part += __shfl_xor(part, 16);
            part += __shfl_xor(part, 32);
            if (g == 0) c_part[p][w][h] = part;
        }

        // 10. finish c of batch b-1 (written last iter into buffer p^1;
        //     separated from those writes by this iteration's barrier)
        if (j > 0 && tid < NH) {
            const int q = p ^ 1;
            float tot = c_part[q][0][tid] + c_part[q][1][tid] + c_part[q][2][tid] + c_part[q][3][tid];
            out_c[(size_t)(b - 1) * NH + tid] = tot * (1.0f / 63.0f);
        }
    }

    // epilogue: final c
    asm volatile("s_waitcnt lgkmcnt(0)" ::: "memory");
    __builtin_amdgcn_s_barrier();
    asm volatile("" ::: "memory");
    if (tid < NH) {
        const int q = (NB - 1) & 1;
        float tot = c_part[q][0][tid] + c_part[q][1][tid] + c_part[q][2][tid] + c_part[q][3][tid];
        out_c[(size_t)(bbase + NB - 1) * NH + tid] = tot * (1.0f / 63.0f);
    }
}

// ---- kernel 2: bilinear logits via MFMA; one wave = 16 batches ----
__global__ __launch_bounds__(256) void bilinear_k(
    const float* __restrict__ hmv, const float* __restrict__ c,
    const unsigned short* __restrict__ wsB, const float* __restrict__ b_bil,
    float* __restrict__ logits)
{
    const int tid = threadIdx.x;
    const int w   = tid >> 6;
    const int l   = tid & 63;
    const int m   = l & 15;
    const int g   = l >> 4;
    const int bgrp = (blockIdx.x * 4 + w) * 16;    // 16 batches per wave

    const float4* hp = reinterpret_cast<const float4*>(hmv + (size_t)(bgrp + m) * NH);
    short8 af[2];
    af[0] = cvt8(hp[0 + 2 * g], hp[1 + 2 * g]);
    af[1] = cvt8(hp[8 + 2 * g], hp[9 + 2 * g]);

    const short8* wl = reinterpret_cast<const short8*>(wsB);
    f32x4 acc[4];
    #pragma unroll
    for (int nt = 0; nt < 4; ++nt)
        for (int r = 0; r < 4; ++r) acc[nt][r] = 0.f;
    #pragma unroll
    for (int kk = 0; kk < 2; ++kk) {
        #pragma unroll
        for (int nt = 0; nt < 4; ++nt) {
            short8 bf = wl[(kk * 4 + nt) * 64 + l];
            acc[nt] = __builtin_amdgcn_mfma_f32_16x16x32_bf16(af[kk], bf, acc[nt], 0, 0, 0);
        }
    }
    // lane holds v[b = bgrp+4g+r][j = 16nt+m]

    float t0[4] = {0.f, 0.f, 0.f, 0.f};
    float t1[4] = {0.f, 0.f, 0.f, 0.f};
    #pragma unroll
    for (int nt = 0; nt < 4; ++nt) {
        #pragma unroll
        for (int r = 0; r < 4; ++r) {
            const int bq = bgrp + 4 * g + r;
            const int bp = (bq == 0) ? (BB - 2) : (bq - 1);
            float cj = c[(size_t)bq * NH + 16 * nt + m];
            float cp = c[(size_t)bp * NH + 16 * nt + m];
            t0[r] = fmaf(acc[nt][r], cj, t0[r]);
            t1[r] = fmaf(acc[nt][r], cp, t1[r]);
        }
    }
    #pragma unroll
    for (int r = 0; r < 4; ++r) {
        #pragma unroll
        for (int off = 1; off < 16; off <<= 1) {
            t0[r] += __shfl_xor(t0[r], off);
            t1[r] += __shfl_xor(t1[r], off);
        }
    }
    if (m == 0) {
        const float bbv = b_bil[0];
        #pragma unroll
        for (int r = 0; r < 4; ++r) {
            const int bq = bgrp + 4 * g + r;
            logits[bq]      = t0[r] + bbv;
            logits[BB + bq] = t1[r] + bbv;
        }
    }
}

extern "C" void kernel_launch(void* const* d_in, const int* in_sizes, int n_in,
                              void* d_out, int out_size, void* d_ws, size_t ws_size,
                              hipStream_t stream) {
    const float* seq1    = (const float*)d_in[0];
    const float* adj     = (const float*)d_in[1];
    const float* W_fc    = (const float*)d_in[2];
    const float* b_gcn   = (const float*)d_in[3];
    const float* prelu_a = (const float*)d_in[4];
    const float* W_bil   = (const float*)d_in[5];
    const float* b_bil   = (const float*)d_in[6];

    float* out    = (float*)d_out;
    float* logits = out;                       // 2*BB
    float* hmv    = out + 2 * BB;              // BB*NH
    float* cc     = hmv + (size_t)BB * NH;     // BB*NH

    unsigned short* wsB = (unsigned short*)d_ws;        // 8 KiB W_bil frags

    conv_wbil<<<(NH * NH + 255) / 256, 256, 0, stream>>>(W_bil, wsB);
    fused_gcn<<<GRID, 256, 0, stream>>>(seq1, adj, W_fc, b_gcn, prelu_a, hmv, cc);
    bilinear_k<<<BB / 64, 256, 0, stream>>>(hmv, cc, wsB, b_bil, logits);
}

// Round 5
// 83.579 us; speedup vs baseline: 1.0949x; 1.0949x over previous
//
#include <hip/hip_runtime.h>
#include <hip/hip_bf16.h>

#define BB   8192
#define SS   64
#define NIN  128
#define NH   64
#define NB   8            // batches per block (fused kernel)
#define GRID (BB / NB)    // 1024 = 4 blocks/CU exactly

typedef __attribute__((ext_vector_type(8))) short  short8;
typedef __attribute__((ext_vector_type(4))) float  f32x4;
typedef __attribute__((ext_vector_type(4))) float  fvec4;

__device__ __forceinline__ short f2bs(float f) {
    union { __hip_bfloat16 h; unsigned short s; } u;
    u.h = __float2bfloat16(f);           // RNE; compiler can pair into v_cvt_pk_bf16_f32
    return (short)u.s;
}

__device__ __forceinline__ short8 cvt8(fvec4 x0, fvec4 x1) {
    short8 r;
    #pragma unroll
    for (int i = 0; i < 4; ++i) { r[i] = f2bs(x0[i]); r[i + 4] = f2bs(x1[i]); }
    return r;
}

__device__ __forceinline__ fvec4 ldnt(const fvec4* p) {
    return __builtin_nontemporal_load(p);     // read-once stream: nt hint
}

// ---- kernel 1: persistent fused GCN, ONE barrier per iteration ----
__global__ __launch_bounds__(256, 4) void fused_gcn(
    const float* __restrict__ seq1, const float* __restrict__ adj,
    const float* __restrict__ W_fc, const float* __restrict__ b_gcn,
    const float* __restrict__ prelu_a, float* __restrict__ out_hmv,
    float* __restrict__ out_c)
{
    __shared__ short8 Wlds[1024];                 // 16 KiB fragment-ordered W_fc
    __shared__ unsigned short ftsT[2][NH][72];    // 18 KiB double-buffered [h][s]
    __shared__ float c_part[2][4][NH];            //  2 KiB double-buffered

    const int tid = threadIdx.x;
    const int w   = tid >> 6;
    const int l   = tid & 63;
    const int m   = l & 15;
    const int g   = l >> 4;
    const int bbase = blockIdx.x * NB;
    const int srow  = 16 * w + m;
    const int s0i   = 16 * w + 4 * g;

    // ---- prologue: issue batch-0 prefetch FIRST (deepest in queue) ----
    fvec4 s0, s1, s2, s3, s4, s5, s6, s7;
    fvec4 a0, a1, a2, a3;
    {
        const fvec4* sp = reinterpret_cast<const fvec4*>(seq1 + (size_t)bbase * (SS * NIN) + srow * NIN);
        s0 = ldnt(sp + 0 + 2 * g);  s1 = ldnt(sp + 1 + 2 * g);
        s2 = ldnt(sp + 8 + 2 * g);  s3 = ldnt(sp + 9 + 2 * g);
        s4 = ldnt(sp + 16 + 2 * g); s5 = ldnt(sp + 17 + 2 * g);
        s6 = ldnt(sp + 24 + 2 * g); s7 = ldnt(sp + 25 + 2 * g);
        const fvec4* ap = reinterpret_cast<const fvec4*>(adj + (size_t)bbase * (SS * SS) + srow * SS);
        a0 = ldnt(ap + 0 + 2 * g); a1 = ldnt(ap + 1 + 2 * g);
        a2 = ldnt(ap + 8 + 2 * g); a3 = ldnt(ap + 9 + 2 * g);
    }

    // ---- build W fragments in-block (W_fc is L2-resident): wave w owns hj=w ----
    #pragma unroll
    for (int kk = 0; kk < 4; ++kk) {
        const fvec4* wp = reinterpret_cast<const fvec4*>(W_fc + (16 * w + m) * NIN + 32 * kk + 8 * g);
        Wlds[(w * 4 + kk) * 64 + l] = cvt8(wp[0], wp[1]);
    }

    const float pa = *prelu_a;
    float bg[4];
    #pragma unroll
    for (int hj = 0; hj < 4; ++hj) bg[hj] = b_gcn[16 * hj + m];

    // raw barrier: W staged; batch-0 prefetch stays in flight
    asm volatile("s_waitcnt lgkmcnt(0)" ::: "memory");
    __builtin_amdgcn_s_barrier();
    asm volatile("" ::: "memory");

    #pragma unroll 1
    for (int j = 0; j < NB; ++j) {
        const int b = bbase + j;
        const int p = j & 1;

        // 1. cvt seq(j)  [counted vmcnt: adj(j) stays outstanding]
        short8 af[4];
        af[0] = cvt8(s0, s1); af[1] = cvt8(s2, s3);
        af[2] = cvt8(s4, s5); af[3] = cvt8(s6, s7);

        // 2. issue seq(j+1)
        if (j + 1 < NB) {
            const fvec4* sp = reinterpret_cast<const fvec4*>(seq1 + (size_t)(b + 1) * (SS * NIN) + srow * NIN);
            s0 = ldnt(sp + 0 + 2 * g);  s1 = ldnt(sp + 1 + 2 * g);
            s2 = ldnt(sp + 8 + 2 * g);  s3 = ldnt(sp + 9 + 2 * g);
            s4 = ldnt(sp + 16 + 2 * g); s5 = ldnt(sp + 17 + 2 * g);
            s6 = ldnt(sp + 24 + 2 * g); s7 = ldnt(sp + 25 + 2 * g);
        }

        // 3. GEMM1: fts[s][h] = sum_i seq[s][i] * W_fc[h][i]
        f32x4 acc1[4];
        #pragma unroll
        for (int hj = 0; hj < 4; ++hj)
            for (int r = 0; r < 4; ++r) acc1[hj][r] = 0.f;
        #pragma unroll
        for (int hj = 0; hj < 4; ++hj) {
            #pragma unroll
            for (int kk = 0; kk < 4; ++kk) {
                short8 bf = Wlds[(hj * 4 + kk) * 64 + l];
                acc1[hj] = __builtin_amdgcn_mfma_f32_16x16x32_bf16(af[kk], bf, acc1[hj], 0, 0, 0);
            }
        }

        // 4. cvt adj(j)  [counted vmcnt: seq(j+1) stays outstanding]
        short8 adf0 = cvt8(a0, a1);
        short8 adf1 = cvt8(a2, a3);

        // 5. issue adj(j+1)  (regs just died -> same VGPRs, full-iteration cover)
        if (j + 1 < NB) {
            const fvec4* ap = reinterpret_cast<const fvec4*>(adj + (size_t)(b + 1) * (SS * SS) + srow * SS);
            a0 = ldnt(ap + 0 + 2 * g); a1 = ldnt(ap + 1 + 2 * g);
            a2 = ldnt(ap + 8 + 2 * g); a3 = ldnt(ap + 9 + 2 * g);
        }

        // 6. pack + transpose-write fts^T to LDS buffer p
        #pragma unroll
        for (int hj = 0; hj < 4; ++hj) {
            unsigned short q0 = (unsigned short)f2bs(acc1[hj][0]);
            unsigned short q1 = (unsigned short)f2bs(acc1[hj][1]);
            unsigned short q2 = (unsigned short)f2bs(acc1[hj][2]);
            unsigned short q3 = (unsigned short)f2bs(acc1[hj][3]);
            uint2 pk;
            pk.x = (unsigned)q0 | ((unsigned)q1 << 16);
            pk.y = (unsigned)q2 | ((unsigned)q3 << 16);
            *reinterpret_cast<uint2*>(&ftsT[p][16 * hj + m][s0i]) = pk;
        }

        // 7. the ONLY barrier this iteration (no vmcnt drain)
        asm volatile("s_waitcnt lgkmcnt(0)" ::: "memory");
        __builtin_amdgcn_s_barrier();
        asm volatile("" ::: "memory");

        // 8. GEMM2: out[s][h] = sum_t adj[s][t] * fts[t][h]
        f32x4 acc2[4];
        #pragma unroll
        for (int hj = 0; hj < 4; ++hj)
            for (int r = 0; r < 4; ++r) acc2[hj][r] = 0.f;
        #pragma unroll
        for (int hj = 0; hj < 4; ++hj) {
            short8 f0 = *reinterpret_cast<const short8*>(&ftsT[p][16 * hj + m][8 * g]);
            short8 f1 = *reinterpret_cast<const short8*>(&ftsT[p][16 * hj + m][8 * g + 32]);
            acc2[hj] = __builtin_amdgcn_mfma_f32_16x16x32_bf16(adf0, f0, acc2[hj], 0, 0, 0);
            acc2[hj] = __builtin_amdgcn_mfma_f32_16x16x32_bf16(adf1, f1, acc2[hj], 0, 0, 0);
        }

        // 9. bias + PReLU + strip sums + h_mv row
        #pragma unroll
        for (int hj = 0; hj < 4; ++hj) {
            const int h = 16 * hj + m;
            float part = 0.f;
            #pragma unroll
            for (int r = 0; r < 4; ++r) {
                float v = acc2[hj][r] + bg[hj];
                v = (v >= 0.f) ? v : pa * v;
                const int s = s0i + r;
                if (s < SS - 1) part += v;
                else            out_hmv[(size_t)b * NH + h] = v;  // s == 63
            }
            part += __shfl_xor(part, 16);
            part += __shfl_xor(part, 32);
            if (g == 0) c_part[p][w][h] = part;
        }

        // 10. finish c of batch b-1 (buffer p^1; protected by this iter's barrier)
        if (j > 0 && tid < NH) {
            const int q = p ^ 1;
            float tot = c_part[q][0][tid] + c_part[q][1][tid] + c_part[q][2][tid] + c_part[q][3][tid];
            out_c[(size_t)(b - 1) * NH + tid] = tot * (1.0f / 63.0f);
        }
    }

    // epilogue: final c
    asm volatile("s_waitcnt lgkmcnt(0)" ::: "memory");
    __builtin_amdgcn_s_barrier();
    asm volatile("" ::: "memory");
    if (tid < NH) {
        const int q = (NB - 1) & 1;
        float tot = c_part[q][0][tid] + c_part[q][1][tid] + c_part[q][2][tid] + c_part[q][3][tid];
        out_c[(size_t)(bbase + NB - 1) * NH + tid] = tot * (1.0f / 63.0f);
    }
}

// ---- kernel 2: bilinear logits via MFMA; W_bil staged+reordered in-kernel ----
__global__ __launch_bounds__(256) void bilinear_k(
    const float* __restrict__ hmv, const float* __restrict__ c,
    const float* __restrict__ wbil, const float* __restrict__ b_bil,
    float* __restrict__ logits)
{
    __shared__ short8 wb[512];   // 8 KiB fragment-ordered W_bil (B-operand: k=i, n=j)

    const int tid = threadIdx.x;
    const int w   = tid >> 6;
    const int l   = tid & 63;
    const int m   = l & 15;
    const int g   = l >> 4;
    const int bgrp = (blockIdx.x * 4 + w) * 16;    // 16 batches per wave

    // A frags first (long-latency loads deepest in queue)
    const fvec4* hp = reinterpret_cast<const fvec4*>(hmv + (size_t)(bgrp + m) * NH);
    fvec4 h0 = hp[0 + 2 * g], h1 = hp[1 + 2 * g];
    fvec4 h2 = hp[8 + 2 * g], h3 = hp[9 + 2 * g];

    // stage + frag-reorder W_bil: wb[((kk*4+nt)*64 + g*16+m)*8 + e] = W_bil[32kk+8g+e][16nt+m]
    short* wbs = reinterpret_cast<short*>(wb);
    for (int q = tid; q < NH * NH; q += 256) {
        int i = q >> 6, jj = q & 63;
        int kk = i >> 5, g2 = (i >> 3) & 3, e = i & 7, nt = jj >> 4, mm = jj & 15;
        wbs[(((kk * 4 + nt) * 64) + g2 * 16 + mm) * 8 + e] = f2bs(wbil[q]);
    }
    __syncthreads();

    short8 af[2];
    af[0] = cvt8(h0, h1);
    af[1] = cvt8(h2, h3);

    f32x4 acc[4];
    #pragma unroll
    for (int nt = 0; nt < 4; ++nt)
        for (int r = 0; r < 4; ++r) acc[nt][r] = 0.f;
    #pragma unroll
    for (int kk = 0; kk < 2; ++kk) {
        #pragma unroll
        for (int nt = 0; nt < 4; ++nt) {
            short8 bf = wb[(kk * 4 + nt) * 64 + l];
            acc[nt] = __builtin_amdgcn_mfma_f32_16x16x32_bf16(af[kk], bf, acc[nt], 0, 0, 0);
        }
    }
    // lane holds v[b = bgrp+4g+r][j = 16nt+m]

    float t0[4] = {0.f, 0.f, 0.f, 0.f};
    float t1[4] = {0.f, 0.f, 0.f, 0.f};
    #pragma unroll
    for (int nt = 0; nt < 4; ++nt) {
        #pragma unroll
        for (int r = 0; r < 4; ++r) {
            const int bq = bgrp + 4 * g + r;
            const int bp = (bq == 0) ? (BB - 2) : (bq - 1);
            float cj = c[(size_t)bq * NH + 16 * nt + m];
            float cp = c[(size_t)bp * NH + 16 * nt + m];
            t0[r] = fmaf(acc[nt][r], cj, t0[r]);
            t1[r] = fmaf(acc[nt][r], cp, t1[r]);
        }
    }
    #pragma unroll
    for (int r = 0; r < 4; ++r) {
        #pragma unroll
        for (int off = 1; off < 16; off <<= 1) {
            t0[r] += __shfl_xor(t0[r], off);
            t1[r] += __shfl_xor(t1[r], off);
        }
    }
    if (m == 0) {
        const float bbv = b_bil[0];
        #pragma unroll
        for (int r = 0; r < 4; ++r) {
            const int bq = bgrp + 4 * g + r;
            logits[bq]      = t0[r] + bbv;
            logits[BB + bq] = t1[r] + bbv;
        }
    }
}

extern "C" void kernel_launch(void* const* d_in, const int* in_sizes, int n_in,
                              void* d_out, int out_size, void* d_ws, size_t ws_size,
                              hipStream_t stream) {
    const float* seq1    = (const float*)d_in[0];
    const float* adj     = (const float*)d_in[1];
    const float* W_fc    = (const float*)d_in[2];
    const float* b_gcn   = (const float*)d_in[3];
    const float* prelu_a = (const float*)d_in[4];
    const float* W_bil   = (const float*)d_in[5];
    const float* b_bil   = (const float*)d_in[6];

    float* out    = (float*)d_out;
    float* logits = out;                       // 2*BB
    float* hmv    = out + 2 * BB;              // BB*NH
    float* cc     = hmv + (size_t)BB * NH;     // BB*NH

    fused_gcn<<<GRID, 256, 0, stream>>>(seq1, adj, W_fc, b_gcn, prelu_a, hmv, cc);
    bilinear_k<<<BB / 64, 256, 0, stream>>>(hmv, cc, W_bil, b_bil, logits);
}